// Round 6
// baseline (297.285 us; speedup 1.0000x reference)
//
#include <hip/hip_runtime.h>

#define B_   2
#define LQ   1024
#define LIN  4096
#define CH   256
#define MH   8
#define NP   4
#define NROW (B_ * LQ)                  // 2048 (b,q) rows
#define NPTS (NROW * MH * NP)           // 65536 sampling points

// spatial hash grid for exact KNN: 16^3 cells over [-5.12, 5.12]
#define GN   16
#define GN3  (GN * GN * GN)             // 4096 cells
#define GH   0.64f
#define GX0  (-5.12f)
#define GINV 1.5625f                    // 1/GH
#define GEPS 1e-3f                      // pruning slack (absolute, on squared dist)

// LDS row-swizzle: element (r,k) stored at [r][k ^ SWZ(r)]; SWZ is 4-aligned
// so b128 k-chunks stay contiguous and column-frag reads across 8 row-groups
// land in distinct banks (<=2-way).
#define SWZ(r) ((((r) >> 2) & 7) << 2)

// ---------------------------------------------------------------------------
// Fused S-path: S = query @ [Ws;Wa]^T + [bs;ba] (2048 x 128), then directly
//   loc[b,q,m,p,:] = query_points + S[row][m*12+p*3+e]
//   attw[b,q,m,p]  = softmax_p(S[row][96+m*4+p])
// 32 rows x 128 cols per block -> 64 blocks. 256 threads, 2x8 micro, BK=16.
// ---------------------------------------------------------------------------
__global__ __launch_bounds__(256)
void gemm_s_fused(const float* __restrict__ query,
                  const float* __restrict__ Ws, const float* __restrict__ bs,
                  const float* __restrict__ Wa, const float* __restrict__ ba,
                  const float* __restrict__ qpts,
                  float* __restrict__ loc, float* __restrict__ attw) {
    __shared__ float As[16][32];
    __shared__ float Bs[16][128];
    __shared__ float Ss[32][132];
    const int tid = threadIdx.x;
    const int rowbase = blockIdx.x * 32;
    const int tx = tid & 15;          // col group (8 cols)
    const int ty = tid >> 4;          // row group (2 rows)

    const int lr  = tid >> 3;         // A-staging row 0..31
    const int lka = (tid & 7) * 2;    // A-staging k (float2)
    const float* Ap = query + (size_t)(rowbase + lr) * CH + lka;
    const int n   = tid >> 1;         // B-staging weight row
    const int lkb = (tid & 1) * 8;
    const float* Wrow = ((n < 96) ? (Ws + (size_t)n * CH)
                                  : (Wa + (size_t)(n - 96) * CH)) + lkb;
    float bj[8];
#pragma unroll
    for (int j = 0; j < 8; ++j) {
        int col = tx * 8 + j;
        bj[j] = (col < 96) ? bs[col] : ba[col - 96];
    }

    float2 a0 = *reinterpret_cast<const float2*>(Ap);
    float4 b0 = *reinterpret_cast<const float4*>(Wrow);
    float4 b1 = *reinterpret_cast<const float4*>(Wrow + 4);

    float acc[2][8] = {};
    for (int k0 = 0; k0 < CH; k0 += 16) {
        __syncthreads();
        As[lka + 0][lr] = a0.x; As[lka + 1][lr] = a0.y;
        Bs[lkb + 0][n] = b0.x; Bs[lkb + 1][n] = b0.y;
        Bs[lkb + 2][n] = b0.z; Bs[lkb + 3][n] = b0.w;
        Bs[lkb + 4][n] = b1.x; Bs[lkb + 5][n] = b1.y;
        Bs[lkb + 6][n] = b1.z; Bs[lkb + 7][n] = b1.w;
        __syncthreads();
        if (k0 + 16 < CH) {
            a0 = *reinterpret_cast<const float2*>(Ap + k0 + 16);
            b0 = *reinterpret_cast<const float4*>(Wrow + k0 + 16);
            b1 = *reinterpret_cast<const float4*>(Wrow + k0 + 20);
        }
#pragma unroll
        for (int k = 0; k < 16; ++k) {
            float2 a  = *reinterpret_cast<const float2*>(&As[k][ty << 1]);
            float4 v0 = *reinterpret_cast<const float4*>(&Bs[k][tx * 8]);
            float4 v1 = *reinterpret_cast<const float4*>(&Bs[k][tx * 8 + 4]);
            float ar[2] = {a.x, a.y};
            float br[8] = {v0.x, v0.y, v0.z, v0.w, v1.x, v1.y, v1.z, v1.w};
#pragma unroll
            for (int i = 0; i < 2; ++i)
#pragma unroll
                for (int j = 0; j < 8; ++j)
                    acc[i][j] = fmaf(ar[i], br[j], acc[i][j]);
        }
    }

    __syncthreads();
#pragma unroll
    for (int i = 0; i < 2; ++i)
#pragma unroll
        for (int j = 0; j < 8; ++j)
            Ss[ty * 2 + i][tx * 8 + j] = acc[i][j] + bj[j];
    __syncthreads();

    {   // epilogue: 256 units = 32 rows x 8 heads
        int row = tid >> 3;
        int m   = tid & 7;
        int r   = rowbase + row;
        const float* Sr = Ss[row];
        float q0 = qpts[r * 3 + 0], q1 = qpts[r * 3 + 1], q2 = qpts[r * 3 + 2];
#pragma unroll
        for (int p = 0; p < NP; ++p) {
            size_t o = ((size_t)(r * MH + m) * NP + p) * 3;
            loc[o + 0] = q0 + Sr[m * 12 + p * 3 + 0];
            loc[o + 1] = q1 + Sr[m * 12 + p * 3 + 1];
            loc[o + 2] = q2 + Sr[m * 12 + p * 3 + 2];
        }
        float l0 = Sr[96 + m * 4 + 0], l1 = Sr[96 + m * 4 + 1];
        float l2 = Sr[96 + m * 4 + 2], l3 = Sr[96 + m * 4 + 3];
        float mx = fmaxf(fmaxf(l0, l1), fmaxf(l2, l3));
        float e0 = expf(l0 - mx), e1 = expf(l1 - mx);
        float e2 = expf(l2 - mx), e3 = expf(l3 - mx);
        float inv = 1.0f / (e0 + e1 + e2 + e3);
        size_t ao = (size_t)(r * MH + m) * NP;
        attw[ao + 0] = e0 * inv; attw[ao + 1] = e1 * inv;
        attw[ao + 2] = e2 * inv; attw[ao + 3] = e3 * inv;
    }
}

// ---------------------------------------------------------------------------
// Counting-sort the candidate points into a 16^3 grid (per batch).
// Output: spts[b][pos] = (x, y, z, bits(orig_idx)) sorted by cell;
//         cellstart[b][c..c+1) gives each cell's range (4097 entries).
// One block per batch, 512 threads; hist(16KB)+scan in LDS.
// ---------------------------------------------------------------------------
__global__ __launch_bounds__(512)
void build_grid_kernel(const float* __restrict__ ipts,
                       float4* __restrict__ spts, int* __restrict__ cellstart) {
    __shared__ int hist[GN3];
    __shared__ int part[512];
    const int b = blockIdx.x;
    const int t = threadIdx.x;
    const float* pb = ipts + (size_t)b * LIN * 3;

#pragma unroll
    for (int k = 0; k < GN3 / 512; ++k) hist[k * 512 + t] = 0;
    __syncthreads();

    int cells[LIN / 512];
#pragma unroll
    for (int k = 0; k < LIN / 512; ++k) {
        int i = k * 512 + t;
        float x = pb[i * 3 + 0], y = pb[i * 3 + 1], z = pb[i * 3 + 2];
        int cx = min(max((int)floorf((x - GX0) * GINV), 0), GN - 1);
        int cy = min(max((int)floorf((y - GX0) * GINV), 0), GN - 1);
        int cz = min(max((int)floorf((z - GX0) * GINV), 0), GN - 1);
        cells[k] = (cz * GN + cy) * GN + cx;
        atomicAdd(&hist[cells[k]], 1);
    }
    __syncthreads();

    // exclusive scan over 4096: per-thread serial(8) + Hillis-Steele(512)
    int h8[8];
    int sum = 0;
#pragma unroll
    for (int k = 0; k < 8; ++k) { h8[k] = hist[t * 8 + k]; sum += h8[k]; }
    part[t] = sum;
    __syncthreads();
    for (int off = 1; off < 512; off <<= 1) {
        int v = (t >= off) ? part[t - off] : 0;
        __syncthreads();
        part[t] += v;
        __syncthreads();
    }
    int base = part[t] - sum;            // exclusive prefix of thread's 8 cells
    const int cb = b * (GN3 + 1);
#pragma unroll
    for (int k = 0; k < 8; ++k) {
        int c = t * 8 + k;
        cellstart[cb + c] = base;
        hist[c] = base;                  // becomes the scatter cursor
        base += h8[k];
    }
    if (t == 511) cellstart[cb + GN3] = LIN;
    __syncthreads();

    // scatter (order within a cell is arbitrary; ties are handled
    // order-independently in the knn kernel via (d, orig_idx) lex compare)
#pragma unroll
    for (int k = 0; k < LIN / 512; ++k) {
        int i = k * 512 + t;
        float x = pb[i * 3 + 0], y = pb[i * 3 + 1], z = pb[i * 3 + 2];
        int pos = atomicAdd(&hist[cells[k]], 1);
        spts[(size_t)b * LIN + pos] = make_float4(x, y, z, __int_as_float(i));
    }
}

// ---------------------------------------------------------------------------
// Exact grid KNN: concentric Chebyshev shells from the query's cell.
// Cell pruning: true box distance LB; ring r is >= (r-1)*GH away, so stop
// when ((r-1)*GH)^2 > best + eps. Candidate d uses the identical fmaf
// formula as the (passing) brute-force rounds; the tracked metric is
// |v|^2 - 2 s.v = d_true^2 - |s|^2, so comparisons add ssq back.
// Ties: lexicographic (d, orig_idx) -> first-min, scan-order independent.
// One thread per sampling point; no atomics, no key init.
// ---------------------------------------------------------------------------
__global__ __launch_bounds__(256)
void knn_grid_kernel(const float* __restrict__ loc, const float4* __restrict__ spts,
                     const int* __restrict__ cellstart, int* __restrict__ idx) {
    const int gq = blockIdx.x * 256 + threadIdx.x;   // [0, NPTS)
    const int b  = gq >> 15;                          // 32768 points per batch
    const float sx = loc[(size_t)gq * 3 + 0];
    const float sy = loc[(size_t)gq * 3 + 1];
    const float sz = loc[(size_t)gq * 3 + 2];
    const float sx2 = -2.f * sx, sy2 = -2.f * sy, sz2 = -2.f * sz;
    const float ssq = fmaf(sz, sz, fmaf(sy, sy, sx * sx));

    const int icx = min(max((int)floorf((sx - GX0) * GINV), 0), GN - 1);
    const int icy = min(max((int)floorf((sy - GX0) * GINV), 0), GN - 1);
    const int icz = min(max((int)floorf((sz - GX0) * GINV), 0), GN - 1);

    const int cb = b * (GN3 + 1);
    const float4* sb = spts + (size_t)b * LIN;

    float bd = 1e30f;
    int   bi = 0;

    for (int r = 0; r < GN; ++r) {
        if (r > 0) {
            float rb = (float)(r - 1) * GH;          // ring-r cells are >= rb away
            if (rb * rb > bd + ssq + GEPS) break;
        }
        int zlo = max(icz - r, 0), zhi = min(icz + r, GN - 1);
        int ylo = max(icy - r, 0), yhi = min(icy + r, GN - 1);
        int xlo = max(icx - r, 0), xhi = min(icx + r, GN - 1);
        for (int cz = zlo; cz <= zhi; ++cz) {
            int az = abs(cz - icz);
            for (int cy = ylo; cy <= yhi; ++cy) {
                int ay = max(az, abs(cy - icy));
                for (int cx = xlo; cx <= xhi; ++cx) {
                    if (max(ay, abs(cx - icx)) != r) continue;   // shell only
                    // true box lower bound (squared)
                    float lox = GX0 + cx * GH;
                    float loy = GX0 + cy * GH;
                    float loz = GX0 + cz * GH;
                    float dx = fmaxf(fmaxf(lox - sx, sx - (lox + GH)), 0.f);
                    float dy = fmaxf(fmaxf(loy - sy, sy - (loy + GH)), 0.f);
                    float dz = fmaxf(fmaxf(loz - sz, sz - (loz + GH)), 0.f);
                    float lbsq = fmaf(dx, dx, fmaf(dy, dy, dz * dz));
                    if (lbsq > bd + ssq + GEPS) continue;
                    int c  = (cz * GN + cy) * GN + cx;
                    int s0 = cellstart[cb + c];
                    int s1 = cellstart[cb + c + 1];
                    for (int j = s0; j < s1; ++j) {
                        float4 sp = sb[j];
                        float nrm = fmaf(sp.z, sp.z, fmaf(sp.y, sp.y, sp.x * sp.x));
                        float d   = fmaf(sx2, sp.x, fmaf(sy2, sp.y, fmaf(sz2, sp.z, nrm)));
                        int   oi  = __float_as_int(sp.w);
                        bool take = (d < bd) || (d == bd && oi < bi);
                        bi = take ? oi : bi;
                        bd = fminf(bd, d);
                    }
                }
            }
        }
    }
    idx[gq] = bi;
}

// ---------------------------------------------------------------------------
// blend_gemm: out1_m = (sum_p attw_p * inp[idx_p]) @ Wv_m^T   (per head m)
// sum_p attw = 1 linearity: 16.8M-MAC blend + 134M-MAC thin GEMM replaces
// the 537M-MAC value GEMM + gather. part[ks][((m*NROW+bq)*32+d)]
// ---------------------------------------------------------------------------
__global__ __launch_bounds__(256)
void blend_gemm_kernel(const float* __restrict__ inp, const float* __restrict__ attw,
                       const int* __restrict__ idx,
                       const float* __restrict__ Wv, float* __restrict__ part) {
    __shared__ float Ab[128][132];   // blended rows, k-major, swizzled
    __shared__ float Bs[32][132];    // Wv_m half, k-major, swizzled
    __shared__ int   ids[128][4];
    __shared__ float ats[128][4];
    const int t  = threadIdx.x;
    const int rb = blockIdx.x * 128;     // bq base
    const int m  = blockIdx.y;
    const int ks = blockIdx.z;
    const int k0 = ks * 128;

    if (t < 128) {
        size_t base = ((size_t)(rb + t) * MH + m) * NP;
#pragma unroll
        for (int p = 0; p < NP; ++p) {
            ids[t][p] = idx[base + p];
            ats[t][p] = attw[base + p];
        }
    }
#pragma unroll
    for (int pass = 0; pass < 4; ++pass) {
        int u  = pass * 256 + t;
        int nn = u >> 5;                 // 0..31
        int cg = (u & 31) * 4;           // 0..124
        float4 w = *reinterpret_cast<const float4*>(Wv + (size_t)(m * 32 + nn) * CH + k0 + cg);
        *reinterpret_cast<float4*>(&Bs[nn][cg ^ SWZ(nn)]) = w;
    }
    __syncthreads();

#pragma unroll
    for (int pass = 0; pass < 16; ++pass) {
        int u   = pass * 256 + t;
        int row = u >> 5;                // 0..127
        int cg  = (u & 31) * 4;          // coalesced 512B per row-group
        int bq  = rb + row;
        const float* ib = inp + ((size_t)(bq >> 10) * LIN) * CH + k0 + cg;
        float4 a = {0.f, 0.f, 0.f, 0.f};
#pragma unroll
        for (int p = 0; p < NP; ++p) {
            float4 v = *reinterpret_cast<const float4*>(ib + (size_t)ids[row][p] * CH);
            float w = ats[row][p];
            a.x = fmaf(w, v.x, a.x); a.y = fmaf(w, v.y, a.y);
            a.z = fmaf(w, v.z, a.z); a.w = fmaf(w, v.w, a.w);
        }
        *reinterpret_cast<float4*>(&Ab[row][cg ^ SWZ(row)]) = a;
    }
    __syncthreads();

    const int ty = t >> 3;               // 0..31 -> rows ty*4..
    const int tx = t & 7;                // 0..7  -> cols tx*4..
    const int sA = SWZ(ty * 4);
    const int sB = SWZ(tx * 4);
    float acc[4][4] = {};
    for (int k = 0; k < 128; k += 4) {
        float4 a[4], bb[4];
#pragma unroll
        for (int i = 0; i < 4; ++i)
            a[i] = *reinterpret_cast<const float4*>(&Ab[ty * 4 + i][k ^ sA]);
#pragma unroll
        for (int j = 0; j < 4; ++j)
            bb[j] = *reinterpret_cast<const float4*>(&Bs[tx * 4 + j][k ^ sB]);
#pragma unroll
        for (int i = 0; i < 4; ++i)
#pragma unroll
            for (int j = 0; j < 4; ++j)
                acc[i][j] = fmaf(a[i].x, bb[j].x, fmaf(a[i].y, bb[j].y,
                             fmaf(a[i].z, bb[j].z, fmaf(a[i].w, bb[j].w, acc[i][j]))));
    }
#pragma unroll
    for (int i = 0; i < 4; ++i) {
        int bq = rb + ty * 4 + i;
        float4 c = {acc[i][0], acc[i][1], acc[i][2], acc[i][3]};
        *reinterpret_cast<float4*>(part + ((size_t)ks * MH * NROW + (size_t)m * NROW + bq) * 32 + tx * 4) = c;
    }
}

// ---------------------------------------------------------------------------
// out_gemm: out = (part0 + part1 + bv) @ Wo^T + bo   (2048 x 256, K=256)
// 64x32 tiles -> grid (32,8) = 256 blocks.
// ---------------------------------------------------------------------------
__global__ __launch_bounds__(256)
void out_gemm_kernel(const float* __restrict__ part, const float* __restrict__ bv,
                     const float* __restrict__ Wo, const float* __restrict__ bo,
                     float* __restrict__ out) {
    __shared__ float Ab[64][260];
    __shared__ float Bs[32][260];
    const int t  = threadIdx.x;
    const int rb = blockIdx.x * 64;
    const int nb = blockIdx.y * 32;

#pragma unroll
    for (int pass = 0; pass < 16; ++pass) {
        int u   = pass * 256 + t;
        int row = u >> 6;                // 0..63
        int cg  = (u & 63) * 4;          // 0..252
        int bq  = rb + row;
        int mm  = cg >> 5, d = cg & 31;
        size_t pi = ((size_t)mm * NROW + bq) * 32 + d;
        float4 v0 = *reinterpret_cast<const float4*>(part + pi);
        float4 v1 = *reinterpret_cast<const float4*>(part + (size_t)MH * NROW * 32 + pi);
        float4 bb = *reinterpret_cast<const float4*>(bv + cg);
        float4 a  = {v0.x + v1.x + bb.x, v0.y + v1.y + bb.y,
                     v0.z + v1.z + bb.z, v0.w + v1.w + bb.w};
        *reinterpret_cast<float4*>(&Ab[row][cg ^ SWZ(row)]) = a;
    }
#pragma unroll
    for (int pass = 0; pass < 8; ++pass) {
        int u  = pass * 256 + t;
        int nn = u >> 6;                 // 0..31
        int cg = (u & 63) * 4;
        float4 w = *reinterpret_cast<const float4*>(Wo + (size_t)(nb + nn) * CH + cg);
        *reinterpret_cast<float4*>(&Bs[nn][cg ^ SWZ(nn)]) = w;
    }
    __syncthreads();

    const int ty = t >> 3;               // 0..31 -> rows ty*2..
    const int tx = t & 7;                // 0..7  -> cols tx*4..
    const int sA = SWZ(ty * 2);
    const int sB = SWZ(tx * 4);
    float acc[2][4] = {};
    for (int k = 0; k < 256; k += 4) {
        float4 a[2], bb[4];
#pragma unroll
        for (int i = 0; i < 2; ++i)
            a[i] = *reinterpret_cast<const float4*>(&Ab[ty * 2 + i][k ^ sA]);
#pragma unroll
        for (int j = 0; j < 4; ++j)
            bb[j] = *reinterpret_cast<const float4*>(&Bs[tx * 4 + j][k ^ sB]);
#pragma unroll
        for (int i = 0; i < 2; ++i)
#pragma unroll
            for (int j = 0; j < 4; ++j)
                acc[i][j] = fmaf(a[i].x, bb[j].x, fmaf(a[i].y, bb[j].y,
                             fmaf(a[i].z, bb[j].z, fmaf(a[i].w, bb[j].w, acc[i][j]))));
    }
#pragma unroll
    for (int i = 0; i < 2; ++i) {
        int bq = rb + ty * 2 + i;
        int n  = nb + tx * 4;
        float4 c = {acc[i][0] + bo[n + 0], acc[i][1] + bo[n + 1],
                    acc[i][2] + bo[n + 2], acc[i][3] + bo[n + 3]};
        *reinterpret_cast<float4*>(out + (size_t)bq * CH + n) = c;
    }
}

// ---------------------------------------------------------------------------
extern "C" void kernel_launch(void* const* d_in, const int* in_sizes, int n_in,
                              void* d_out, int out_size, void* d_ws, size_t ws_size,
                              hipStream_t stream) {
    const float* query = (const float*)d_in[0];
    const float* qpts  = (const float*)d_in[1];
    const float* inp   = (const float*)d_in[2];
    const float* ipts  = (const float*)d_in[3];
    const float* Wv    = (const float*)d_in[4];
    const float* bv    = (const float*)d_in[5];
    const float* Ws    = (const float*)d_in[6];
    const float* bs    = (const float*)d_in[7];
    const float* Wa    = (const float*)d_in[8];
    const float* ba    = (const float*)d_in[9];
    const float* Wo    = (const float*)d_in[10];
    const float* bo    = (const float*)d_in[11];
    float* out = (float*)d_out;

    // workspace layout (~5.8 MB); every buffer fully overwritten each call
    float*  ws        = (float*)d_ws;
    float*  loc       = ws;                                  // NPTS*3 f
    float*  attw      = loc + (size_t)NPTS * 3;              // NPTS f
    float*  part      = attw + (size_t)NPTS;                 // 2*MH*NROW*32 f
    float4* spts      = (float4*)(part + (size_t)2 * MH * NROW * 32); // B*LIN f4
    int*    idx       = (int*)(spts + (size_t)B_ * LIN);     // NPTS i
    int*    cellstart = idx + (size_t)NPTS;                  // B*(GN3+1) i

    // 1. counting-sort candidates into the 16^3 grid (independent of 2.)
    build_grid_kernel<<<B_, 512, 0, stream>>>(ipts, spts, cellstart);
    // 2. S-path GEMM -> sampling locations + softmax weights
    gemm_s_fused<<<NROW / 32, 256, 0, stream>>>(query, Ws, bs, Wa, ba, qpts,
                                                loc, attw);
    // 3. exact grid KNN (shell search, ~50-150 candidates/pt vs 4096 brute)
    knn_grid_kernel<<<NPTS / 256, 256, 0, stream>>>(loc, spts, cellstart, idx);
    // 4. gather-blend + per-head value GEMM (134M MAC)
    blend_gemm_kernel<<<dim3(NROW / 128, MH, 2), 256, 0, stream>>>(
        inp, attw, idx, Wv, part);
    // 5. output GEMM, merging K-halves + value bias (134M MAC)
    out_gemm_kernel<<<dim3(NROW / 64, CH / 32), 256, 0, stream>>>(
        part, bv, Wo, bo, out);
}